// Round 1
// baseline (900.754 us; speedup 1.0000x reference)
//
#include <hip/hip_runtime.h>
#include <math.h>

#define NTOK      262144
#define DIM       1024
#define NEXP      64
#define TOPK      8
#define ROWS      128   // rows per block
#define BK        64    // K-chunk (floats)

// out layout (all float32):
//   [0, NTOK*TOPK)              weights
//   [NTOK*TOPK, 2*NTOK*TOPK)    indices (as float values)
//   [2*NTOK*TOPK, +NEXP)        expert usage counts
//   [2*NTOK*TOPK + NEXP]        total_tokens
#define OFF_IDX   ((size_t)NTOK * TOPK)
#define OFF_USE   (2u * (size_t)NTOK * TOPK)
#define OFF_TOT   (OFF_USE + NEXP)

__global__ __launch_bounds__(256) void gate_init_kernel(float* __restrict__ out) {
    int t = threadIdx.x;
    if (t < NEXP) out[OFF_USE + t] = 0.0f;
    if (t == NEXP) out[OFF_TOT] = (float)((size_t)NTOK * TOPK); // 2097152.0f
}

__global__ __launch_bounds__(256) void gate_kernel(const float* __restrict__ x,
                                                   const float* __restrict__ W,
                                                   const float* __restrict__ bias,
                                                   float* __restrict__ out) {
    // xs4: [128 rows][16 float4-cols], XOR-swizzled; 32 KB. Reused for scores.
    __shared__ float4 xs4[ROWS * 16];
    // ws4: [64 experts][16 float4-cols], XOR-swizzled; 16 KB.
    __shared__ float4 ws4[NEXP * 16];
    __shared__ float hist[NEXP];

    const int tid = threadIdx.x;
    const int tr  = tid >> 4;   // 0..15 : row-group (8 rows each)
    const int te  = tid & 15;   // 0..15 : expert-group (4 experts each)
    const int rowBase = blockIdx.x * ROWS;

    if (tid < NEXP) hist[tid] = 0.0f;

    float acc[8][4];
#pragma unroll
    for (int i = 0; i < 8; i++)
#pragma unroll
        for (int j = 0; j < 4; j++) acc[i][j] = 0.0f;

    for (int d0 = 0; d0 < DIM; d0 += BK) {
        __syncthreads();
        // ---- stage x tile: 128 rows x 64 cols = 2048 float4 slots, 8/thread
#pragma unroll
        for (int k = 0; k < 8; k++) {
            int s  = tid + k * 256;
            int r  = s >> 4;
            int d4 = s & 15;
            float4 v = *reinterpret_cast<const float4*>(
                &x[(size_t)(rowBase + r) * DIM + d0 + d4 * 4]);
            xs4[r * 16 + (d4 ^ (r >> 3))] = v;
        }
        // ---- stage W tile: 64 experts x 64 cols = 1024 float4 slots, 4/thread
#pragma unroll
        for (int k = 0; k < 4; k++) {
            int s  = tid + k * 256;
            int e  = s >> 4;
            int d4 = s & 15;
            float4 v = *reinterpret_cast<const float4*>(
                &W[(size_t)e * DIM + d0 + d4 * 4]);
            ws4[e * 16 + (d4 ^ (e >> 2))] = v;
        }
        __syncthreads();
        // ---- fp32 outer-product accumulate
#pragma unroll 4
        for (int d4 = 0; d4 < 16; d4++) {
            float4 wv[4];
#pragma unroll
            for (int j = 0; j < 4; j++)
                wv[j] = ws4[(te * 4 + j) * 16 + (d4 ^ te)];
#pragma unroll
            for (int i = 0; i < 8; i++) {
                float4 xv = xs4[(tr * 8 + i) * 16 + (d4 ^ tr)];
#pragma unroll
                for (int j = 0; j < 4; j++) {
                    acc[i][j] += xv.x * wv[j].x;
                    acc[i][j] += xv.y * wv[j].y;
                    acc[i][j] += xv.z * wv[j].z;
                    acc[i][j] += xv.w * wv[j].w;
                }
            }
        }
    }
    __syncthreads();

    // ---- write scores (+bias) into the x tile LDS, layout [128][64] floats
    float b0 = bias[te * 4 + 0];
    float b1 = bias[te * 4 + 1];
    float b2 = bias[te * 4 + 2];
    float b3 = bias[te * 4 + 3];
#pragma unroll
    for (int i = 0; i < 8; i++) {
        float4 v = make_float4(acc[i][0] + b0, acc[i][1] + b1,
                               acc[i][2] + b2, acc[i][3] + b3);
        xs4[(tr * 8 + i) * 16 + te] = v;
    }
    __syncthreads();

    // ---- softmax + top-8 per row; wave w handles rows [w*32, w*32+32)
    const float* ss = reinterpret_cast<const float*>(xs4);
    const int wave = tid >> 6;
    const int lane = tid & 63;

    float* out_w = out;
    float* out_i = out + OFF_IDX;
    float* usage = out + OFF_USE;

    for (int t = 0; t < 32; t++) {
        int row = wave * 32 + t;
        float sv = ss[row * 64 + lane];

        // row max (64-lane butterfly)
        float m = sv;
#pragma unroll
        for (int off = 32; off; off >>= 1) m = fmaxf(m, __shfl_xor(m, off));
        float ev = expf(sv - m);
        float sum = ev;
#pragma unroll
        for (int off = 32; off; off >>= 1) sum += __shfl_xor(sum, off);
        float p = ev / sum;

        float val = p;          // lane's candidate (expert id = lane)
        float myw = 0.0f;
        int   myi = 0;
#pragma unroll
        for (int k = 0; k < TOPK; k++) {
            float bv = val; int bi = lane;
#pragma unroll
            for (int off = 32; off; off >>= 1) {
                float ov = __shfl_xor(bv, off);
                int   oi = __shfl_xor(bi, off);
                if (ov > bv || (ov == bv && oi < bi)) { bv = ov; bi = oi; }
            }
            if (lane == k) { myw = bv; myi = bi; }
            if (lane == bi) val = -1.0f;   // probs >= 0, so -1 masks out
        }
        if (lane < TOPK) {
            size_t o = (size_t)(rowBase + row) * TOPK + lane;
            out_w[o] = myw;                // ROUTE_SCALE == 1.0
            out_i[o] = (float)myi;
            atomicAdd(&hist[myi], 1.0f);
        }
    }
    __syncthreads();
    if (tid < NEXP) atomicAdd(&usage[tid], hist[tid]);
}

extern "C" void kernel_launch(void* const* d_in, const int* in_sizes, int n_in,
                              void* d_out, int out_size, void* d_ws, size_t ws_size,
                              hipStream_t stream) {
    const float* x    = (const float*)d_in[0];
    const float* W    = (const float*)d_in[1];
    const float* bias = (const float*)d_in[2];
    float* out = (float*)d_out;

    // Zero the usage counters + write total_tokens every call (harness does
    // not re-zero d_out between timed replays; main kernel accumulates).
    gate_init_kernel<<<1, 256, 0, stream>>>(out);

    gate_kernel<<<NTOK / ROWS, 256, 0, stream>>>(x, W, bias, out);
}

// Round 2
// 376.357 us; speedup vs baseline: 2.3933x; 2.3933x over previous
//
#include <hip/hip_runtime.h>
#include <math.h>

#define NTOK   262144
#define DIM    1024
#define NEXP   64
#define TOPK   8
#define ROWS   256     // rows per block (8 waves x 32 rows)
#define BLK    512
#define KSTEP  32
#define SSTR   65      // LDS score row stride (pad: stride%32==1 -> <=2-way, free)

#define OFF_IDX ((size_t)NTOK * TOPK)
#define OFF_USE (2 * (size_t)NTOK * TOPK)
#define OFF_TOT (OFF_USE + NEXP)

typedef __attribute__((ext_vector_type(8))) short bf16x8;
typedef __attribute__((ext_vector_type(4))) float f32x4;

union FragU { bf16x8 v; unsigned int u[4]; };

// truncate 8 f32 -> bf16x8 fragment (RTZ; residual is captured by the lo term on A side)
__device__ __forceinline__ bf16x8 cvt_hi8(float4 a, float4 b) {
    unsigned int u[8];
    u[0]=__float_as_uint(a.x); u[1]=__float_as_uint(a.y);
    u[2]=__float_as_uint(a.z); u[3]=__float_as_uint(a.w);
    u[4]=__float_as_uint(b.x); u[5]=__float_as_uint(b.y);
    u[6]=__float_as_uint(b.z); u[7]=__float_as_uint(b.w);
    FragU r;
#pragma unroll
    for (int i = 0; i < 4; i++)
        r.u[i] = (u[2*i] >> 16) | (u[2*i+1] & 0xFFFF0000u);
    return r.v;
}

// split 8 f32 into hi/lo bf16x8 fragments: x = hi + lo (+O(2^-17))
__device__ __forceinline__ void split8(float4 a, float4 b, bf16x8& hi, bf16x8& lo) {
    float f[8] = {a.x,a.y,a.z,a.w,b.x,b.y,b.z,b.w};
    unsigned int h[8], l[8];
#pragma unroll
    for (int i = 0; i < 8; i++) {
        unsigned int u = __float_as_uint(f[i]);
        h[i] = u & 0xFFFF0000u;                       // hi as f32 bits (truncated)
        l[i] = __float_as_uint(f[i] - __uint_as_float(h[i]));
    }
    FragU H, L;
#pragma unroll
    for (int i = 0; i < 4; i++) {
        H.u[i] = (h[2*i] >> 16) | h[2*i+1];           // h already low-16-clean
        L.u[i] = (l[2*i] >> 16) | (l[2*i+1] & 0xFFFF0000u);
    }
    hi = H.v; lo = L.v;
}

__global__ __launch_bounds__(256) void gate_init_kernel(float* __restrict__ out) {
    int t = threadIdx.x;
    if (t < NEXP) out[OFF_USE + t] = 0.0f;
    if (t == NEXP) out[OFF_TOT] = (float)((size_t)NTOK * TOPK); // 2097152.0f
}

__global__ __launch_bounds__(BLK, 2) void gate_kernel(const float* __restrict__ x,
                                                      const float* __restrict__ W,
                                                      const float* __restrict__ bias,
                                                      float* __restrict__ out) {
    __shared__ float ss[ROWS * SSTR];   // scores [256 rows][65]
    __shared__ float hist[NEXP];

    const int tid  = threadIdx.x;
    const int wave = tid >> 6;
    const int lane = tid & 63;
    const int fr   = lane & 15;   // MFMA fragment row/col
    const int fq   = lane >> 4;   // k-group / accumulator row group
    const size_t rowBase = (size_t)blockIdx.x * ROWS;
    const size_t waveRow = rowBase + (size_t)wave * 32;

    if (tid < NEXP) hist[tid] = 0.0f;

    // bias per lane for the 4 n-tiles
    float bv[4];
#pragma unroll
    for (int nt = 0; nt < 4; nt++) bv[nt] = bias[nt * 16 + fr];

    f32x4 acc[2][4] = {}; // [m-tile][n-tile]

    const float* xp0 = x + (waveRow + fr) * DIM + fq * 8;       // m-tile 0
    const float* xp1 = xp0 + (size_t)16 * DIM;                  // m-tile 1
    const float* wp  = W + (size_t)fr * DIM + fq * 8;           // n-tile stride 16*DIM

    for (int k0 = 0; k0 < DIM; k0 += KSTEP) {
        // A loads (x from HBM): 2 m-tiles x 32B
        float4 a0 = *(const float4*)(xp0 + k0);
        float4 a0b = *(const float4*)(xp0 + k0 + 4);
        float4 a1 = *(const float4*)(xp1 + k0);
        float4 a1b = *(const float4*)(xp1 + k0 + 4);
        // B loads (W from L2): 4 n-tiles x 32B
        float4 b0 = *(const float4*)(wp + k0);
        float4 b0b = *(const float4*)(wp + k0 + 4);
        float4 b1 = *(const float4*)(wp + (size_t)16 * DIM + k0);
        float4 b1b = *(const float4*)(wp + (size_t)16 * DIM + k0 + 4);
        float4 b2 = *(const float4*)(wp + (size_t)32 * DIM + k0);
        float4 b2b = *(const float4*)(wp + (size_t)32 * DIM + k0 + 4);
        float4 b3 = *(const float4*)(wp + (size_t)48 * DIM + k0);
        float4 b3b = *(const float4*)(wp + (size_t)48 * DIM + k0 + 4);

        bf16x8 bh[4];
        bh[0] = cvt_hi8(b0, b0b); bh[1] = cvt_hi8(b1, b1b);
        bh[2] = cvt_hi8(b2, b2b); bh[3] = cvt_hi8(b3, b3b);
        bf16x8 a0h, a0l, a1h, a1l;
        split8(a0, a0b, a0h, a0l);
        split8(a1, a1b, a1h, a1l);

#pragma unroll
        for (int nt = 0; nt < 4; nt++) {
            acc[0][nt] = __builtin_amdgcn_mfma_f32_16x16x32_bf16(a0h, bh[nt], acc[0][nt], 0, 0, 0);
            acc[0][nt] = __builtin_amdgcn_mfma_f32_16x16x32_bf16(a0l, bh[nt], acc[0][nt], 0, 0, 0);
            acc[1][nt] = __builtin_amdgcn_mfma_f32_16x16x32_bf16(a1h, bh[nt], acc[1][nt], 0, 0, 0);
            acc[1][nt] = __builtin_amdgcn_mfma_f32_16x16x32_bf16(a1l, bh[nt], acc[1][nt], 0, 0, 0);
        }
    }

    // scores (+bias) -> LDS.  C/D layout: col = lane&15, row = (lane>>4)*4 + reg
#pragma unroll
    for (int mt = 0; mt < 2; mt++) {
#pragma unroll
        for (int nt = 0; nt < 4; nt++) {
            int mbase = wave * 32 + mt * 16 + fq * 4;
            int n = nt * 16 + fr;
#pragma unroll
            for (int r = 0; r < 4; r++)
                ss[(mbase + r) * SSTR + n] = acc[mt][nt][r] + bv[nt];
        }
    }
    __syncthreads();

    // epilogue: one thread per row (threads 0..255)
    if (tid < ROWS) {
        const float* rp = ss + tid * SSTR;
        float m = rp[0];
#pragma unroll 8
        for (int e = 1; e < NEXP; e++) m = fmaxf(m, rp[e]);
        float sum = 0.0f;
#pragma unroll 8
        for (int e = 0; e < NEXP; e++) sum += expf(rp[e] - m);
        float rinv = 1.0f / sum;

        float tv[8]; int ti[8];
#pragma unroll
        for (int k = 0; k < 8; k++) { tv[k] = -1.0f; ti[k] = 0; }

#pragma unroll 4
        for (int e = 0; e < NEXP; e++) {
            float p = expf(rp[e] - m) * rinv;
            // branchless descending sorted-insert; strict > keeps
            // ascending-index order among ties (matches lax.top_k)
#pragma unroll
            for (int k = 7; k >= 1; k--) {
                bool up   = p > tv[k-1];
                bool here = p > tv[k];
                float nv = up ? tv[k-1] : (here ? p : tv[k]);
                int   ni = up ? ti[k-1] : (here ? e  : ti[k]);
                tv[k] = nv; ti[k] = ni;
            }
            bool c0 = p > tv[0];
            ti[0] = c0 ? e : ti[0];
            tv[0] = c0 ? p : tv[0];
        }

        size_t ro = (rowBase + tid) * TOPK;
        *(float4*)(out + ro)     = make_float4(tv[0], tv[1], tv[2], tv[3]);
        *(float4*)(out + ro + 4) = make_float4(tv[4], tv[5], tv[6], tv[7]);
        *(float4*)(out + OFF_IDX + ro)     = make_float4((float)ti[0], (float)ti[1], (float)ti[2], (float)ti[3]);
        *(float4*)(out + OFF_IDX + ro + 4) = make_float4((float)ti[4], (float)ti[5], (float)ti[6], (float)ti[7]);
#pragma unroll
        for (int k = 0; k < 8; k++) atomicAdd(&hist[ti[k]], 1.0f);
    }
    __syncthreads();
    if (tid < NEXP) atomicAdd(&out[OFF_USE + tid], hist[tid]);
}

extern "C" void kernel_launch(void* const* d_in, const int* in_sizes, int n_in,
                              void* d_out, int out_size, void* d_ws, size_t ws_size,
                              hipStream_t stream) {
    const float* x    = (const float*)d_in[0];
    const float* W    = (const float*)d_in[1];
    const float* bias = (const float*)d_in[2];
    float* out = (float*)d_out;

    // usage counters + total_tokens re-initialized every call (main kernel accumulates)
    gate_init_kernel<<<1, 256, 0, stream>>>(out);
    gate_kernel<<<NTOK / ROWS, BLK, 0, stream>>>(x, W, bias, out);
}

// Round 3
// 312.595 us; speedup vs baseline: 2.8815x; 1.2040x over previous
//
#include <hip/hip_runtime.h>
#include <math.h>

#define NTOK   262144
#define DIM    1024
#define NEXP   64
#define TOPK   8
#define ROWS   256       // rows per block (8 waves x 32 rows)
#define BLK    512
#define BK     32        // K-chunk in floats (128 B per row)
#define NKC    (DIM / BK)   // 32
#define SSTR   65        // score LDS row stride (stride%32==1 -> conflict-free)

#define OFF_IDX ((size_t)NTOK * TOPK)
#define OFF_USE (2 * (size_t)NTOK * TOPK)
#define OFF_TOT (OFF_USE + NEXP)

typedef __attribute__((ext_vector_type(8))) short bf16x8;
typedef __attribute__((ext_vector_type(4))) float f32x4;

union FragU { bf16x8 v; unsigned int u[4]; };

// pack 8 f32 (a=k0..3, b=k4..7) -> bf16x8 fragment, truncation
__device__ __forceinline__ bf16x8 pack_bf16(float4 a, float4 b) {
    FragU r;
    r.u[0] = (__float_as_uint(a.x) >> 16) | (__float_as_uint(a.y) & 0xFFFF0000u);
    r.u[1] = (__float_as_uint(a.z) >> 16) | (__float_as_uint(a.w) & 0xFFFF0000u);
    r.u[2] = (__float_as_uint(b.x) >> 16) | (__float_as_uint(b.y) & 0xFFFF0000u);
    r.u[3] = (__float_as_uint(b.z) >> 16) | (__float_as_uint(b.w) & 0xFFFF0000u);
    return r.v;
}

// Pre-kernel: W [64][1024] f32 -> bf16 fragments in d_ws, laid out so the main
// loop's B loads are lane-coalesced dwordx4:
//   wf[((kc*4 + nt)*64 + lane)*8 + j] = bf16( W[nt*16 + (lane&15)][kc*32 + (lane>>4)*8 + j] )
// Also initializes usage counters + total_tokens (block 0).
__global__ __launch_bounds__(256) void gate_prep_kernel(const float* __restrict__ W,
                                                        unsigned short* __restrict__ wf,
                                                        float* __restrict__ out) {
    int idx = blockIdx.x * 256 + threadIdx.x;      // 65536 total
    int j    = idx & 7;
    int lane = (idx >> 3) & 63;
    int nt   = (idx >> 9) & 3;
    int kc   = idx >> 11;
    int fq = lane >> 4, fr = lane & 15;
    float v = W[(size_t)(nt * 16 + fr) * DIM + kc * BK + fq * 8 + j];
    unsigned int u = __float_as_uint(v);
    u += 0x7FFFu + ((u >> 16) & 1u);               // RNE to bf16
    wf[idx] = (unsigned short)(u >> 16);

    if (blockIdx.x == 0) {
        if (threadIdx.x < NEXP) out[OFF_USE + threadIdx.x] = 0.0f;
        if (threadIdx.x == NEXP) out[OFF_TOT] = (float)((size_t)NTOK * TOPK);
    }
}

__global__ __launch_bounds__(BLK, 4) void gate_kernel(const float* __restrict__ x,
                                                      const unsigned short* __restrict__ wf,
                                                      const float* __restrict__ bias,
                                                      float* __restrict__ out) {
    // x tile double-buffer [2][256 rows][8 x 16B-slots] (64 KB), aliased with
    // score buffer [256][65] f32 (66.56 KB) used after the K-loop.
    __shared__ __align__(16) char smem[ROWS * SSTR * 4];
    __shared__ float hist[NEXP];

    const int tid  = threadIdx.x;
    const int w    = tid >> 6;
    const int lane = tid & 63;
    const int fq   = lane >> 4;   // 0..3
    const int fr   = lane & 15;   // 0..15
    const size_t rowBase = (size_t)blockIdx.x * ROWS;

    if (tid < NEXP) hist[tid] = 0.0f;

    // ---- staging geometry: instr i covers 16B-slots flat = w*256 + i*64 + lane
    //      row = flat>>3, physical slot sp = flat&7, logical chunk = sp ^ (row&7)
    //      (source pre-swizzle so linear global_load_lds yields swizzled LDS)
    const char* xb = (const char*)(x + rowBase * DIM);
    const char* src[4];
#pragma unroll
    for (int i = 0; i < 4; i++) {
        int flat = w * 256 + i * 64 + lane;
        int row = flat >> 3, sp = flat & 7;
        src[i] = xb + (size_t)row * (DIM * 4) + (sp ^ (row & 7)) * 16;
    }
    const int ldsBase = w * 4096;   // bytes within a 32 KB buffer, instr i at +i*1024

#define STAGE(bufsel, kc)                                                          \
    do {                                                                           \
        _Pragma("unroll")                                                          \
        for (int i_ = 0; i_ < 4; i_++)                                             \
            __builtin_amdgcn_global_load_lds(                                      \
                (const __attribute__((address_space(1))) unsigned int*)(src[i_] + (kc) * (BK * 4)), \
                (__attribute__((address_space(3))) unsigned int*)(smem + (bufsel) * 32768 + ldsBase + i_ * 1024), \
                16, 0, 0);                                                         \
    } while (0)

    // ---- A-fragment ds_read addresses (loop-invariant except buffer select)
    const int r0 = w * 32 + fr;          // m-tile 0 row
    const int r1 = r0 + 16;              // m-tile 1 row
    const int c  = fr & 7;               // row&7 == fr&7 (bases are mult. of 8)
    const int a00 = r0 * 8 + ((fq * 2) ^ c);       // 16B-slot indices
    const int a01 = r0 * 8 + ((fq * 2 + 1) ^ c);
    const int a10 = r1 * 8 + ((fq * 2) ^ c);
    const int a11 = r1 * 8 + ((fq * 2 + 1) ^ c);

    // B fragments: wf[((kc*4+nt)*64 + lane)*8] bf16, one dwordx4 per nt
    const bf16x8* wfv = (const bf16x8*)wf;

    f32x4 acc[2][4] = {};

    STAGE(0, 0);
    __syncthreads();

#pragma unroll 2
    for (int kc = 0; kc < NKC; ++kc) {
        const int buf = kc & 1;
        if (kc + 1 < NKC) STAGE(buf ^ 1, kc + 1);

        bf16x8 bfrag[4];
#pragma unroll
        for (int nt = 0; nt < 4; nt++) bfrag[nt] = wfv[(size_t)(kc * 4 + nt) * 64 + lane];

        const float4* xt = (const float4*)(smem + buf * 32768);
        bf16x8 af0 = pack_bf16(xt[a00], xt[a01]);
        bf16x8 af1 = pack_bf16(xt[a10], xt[a11]);

#pragma unroll
        for (int nt = 0; nt < 4; nt++) {
            acc[0][nt] = __builtin_amdgcn_mfma_f32_16x16x32_bf16(af0, bfrag[nt], acc[0][nt], 0, 0, 0);
            acc[1][nt] = __builtin_amdgcn_mfma_f32_16x16x32_bf16(af1, bfrag[nt], acc[1][nt], 0, 0, 0);
        }
        __syncthreads();
    }

    // ---- scores (+bias) -> LDS [256][65].  C/D: col = fr, row = fq*4 + reg
    float* ss = (float*)smem;
    float bv[4];
#pragma unroll
    for (int nt = 0; nt < 4; nt++) bv[nt] = bias[nt * 16 + fr];
#pragma unroll
    for (int mt = 0; mt < 2; mt++) {
        int mbase = w * 32 + mt * 16 + fq * 4;
#pragma unroll
        for (int nt = 0; nt < 4; nt++) {
            int n = nt * 16 + fr;
#pragma unroll
            for (int r = 0; r < 4; r++)
                ss[(mbase + r) * SSTR + n] = acc[mt][nt][r] + bv[nt];
        }
    }
    __syncthreads();

    // ---- epilogue: one thread per row (threads 0..255)
    if (tid < ROWS) {
        const float* rp = ss + tid * SSTR;
        float m = rp[0];
#pragma unroll 8
        for (int e = 1; e < NEXP; e++) m = fmaxf(m, rp[e]);
        float sum = 0.0f;
#pragma unroll 8
        for (int e = 0; e < NEXP; e++) sum += expf(rp[e] - m);
        float rinv = 1.0f / sum;

        float tv[8]; int ti[8];
#pragma unroll
        for (int k = 0; k < 8; k++) { tv[k] = -1.0f; ti[k] = 0; }

#pragma unroll 4
        for (int e = 0; e < NEXP; e++) {
            float p = expf(rp[e] - m) * rinv;
            // branchless descending sorted-insert; strict > keeps ascending
            // index order among ties (matches lax.top_k)
#pragma unroll
            for (int k = 7; k >= 1; k--) {
                bool up   = p > tv[k - 1];
                bool here = p > tv[k];
                float nv = up ? tv[k - 1] : (here ? p : tv[k]);
                int   ni = up ? ti[k - 1] : (here ? e : ti[k]);
                tv[k] = nv; ti[k] = ni;
            }
            bool c0 = p > tv[0];
            ti[0] = c0 ? e : ti[0];
            tv[0] = c0 ? p : tv[0];
        }

        size_t ro = (rowBase + tid) * TOPK;
        *(float4*)(out + ro)     = make_float4(tv[0], tv[1], tv[2], tv[3]);
        *(float4*)(out + ro + 4) = make_float4(tv[4], tv[5], tv[6], tv[7]);
        *(float4*)(out + OFF_IDX + ro)     = make_float4((float)ti[0], (float)ti[1], (float)ti[2], (float)ti[3]);
        *(float4*)(out + OFF_IDX + ro + 4) = make_float4((float)ti[4], (float)ti[5], (float)ti[6], (float)ti[7]);
#pragma unroll
        for (int k = 0; k < 8; k++) atomicAdd(&hist[ti[k]], 1.0f);
    }
    __syncthreads();
    if (tid < NEXP) atomicAdd(&out[OFF_USE + tid], hist[tid]);
}

extern "C" void kernel_launch(void* const* d_in, const int* in_sizes, int n_in,
                              void* d_out, int out_size, void* d_ws, size_t ws_size,
                              hipStream_t stream) {
    const float* x    = (const float*)d_in[0];
    const float* W    = (const float*)d_in[1];
    const float* bias = (const float*)d_in[2];
    float* out = (float*)d_out;
    unsigned short* wf = (unsigned short*)d_ws;   // 128 KB fragment-ordered bf16 W

    gate_prep_kernel<<<256, 256, 0, stream>>>(W, wf, out);
    gate_kernel<<<NTOK / ROWS, BLK, 0, stream>>>(x, wf, bias, out);
}

// Round 4
// 254.648 us; speedup vs baseline: 3.5373x; 1.2276x over previous
//
#include <hip/hip_runtime.h>
#include <math.h>

#define NTOK   262144
#define DIM    1024
#define NEXP   64
#define TOPK   8
#define ROWS   256          // rows per block = 8 waves x 32 rows
#define BLK    512
#define BK     32           // K-chunk (floats) = 128 B per row
#define NKC    (DIM / BK)   // 32 K-steps
#define SLICE  8512         // per-wave LDS slice: 2x4096 stage + score overflow

#define OFF_IDX ((size_t)NTOK * TOPK)
#define OFF_USE (2 * (size_t)NTOK * TOPK)
#define OFF_TOT (OFF_USE + NEXP)

typedef __attribute__((ext_vector_type(8))) short bf16x8;
typedef __attribute__((ext_vector_type(4))) float f32x4;

union FragU { bf16x8 v; unsigned int u[4]; };

// pack 8 f32 (a=k0..3, b=k4..7) -> bf16x8 fragment (truncate)
__device__ __forceinline__ bf16x8 pack_bf16(float4 a, float4 b) {
    FragU r;
    r.u[0] = (__float_as_uint(a.x) >> 16) | (__float_as_uint(a.y) & 0xFFFF0000u);
    r.u[1] = (__float_as_uint(a.z) >> 16) | (__float_as_uint(a.w) & 0xFFFF0000u);
    r.u[2] = (__float_as_uint(b.x) >> 16) | (__float_as_uint(b.y) & 0xFFFF0000u);
    r.u[3] = (__float_as_uint(b.z) >> 16) | (__float_as_uint(b.w) & 0xFFFF0000u);
    return r.v;
}

// W [64][1024] f32 -> bf16 MFMA B-fragments in d_ws:
//   wf[((kc*4+nt)*64 + lane)*8 + j] = bf16(W[nt*16+(lane&15)][kc*32+(lane>>4)*8+j])
// Also init usage counters + total_tokens.
__global__ __launch_bounds__(256) void gate_prep_kernel(const float* __restrict__ W,
                                                        unsigned short* __restrict__ wf,
                                                        float* __restrict__ out) {
    int idx = blockIdx.x * 256 + threadIdx.x;      // 65536 total
    int j    = idx & 7;
    int lane = (idx >> 3) & 63;
    int nt   = (idx >> 9) & 3;
    int kc   = idx >> 11;
    int fq = lane >> 4, fr = lane & 15;
    float v = W[(size_t)(nt * 16 + fr) * DIM + kc * BK + fq * 8 + j];
    unsigned int u = __float_as_uint(v);
    u += 0x7FFFu + ((u >> 16) & 1u);               // RNE to bf16
    wf[idx] = (unsigned short)(u >> 16);

    if (blockIdx.x == 0) {
        if (threadIdx.x < NEXP) out[OFF_USE + threadIdx.x] = 0.0f;
        if (threadIdx.x == NEXP) out[OFF_TOT] = (float)((size_t)NTOK * TOPK);
    }
}

__global__ __launch_bounds__(BLK, 4) void gate_kernel(const float* __restrict__ x,
                                                      const unsigned short* __restrict__ wf,
                                                      const float* __restrict__ bias,
                                                      float* __restrict__ out) {
    // Per-wave private slices: [8 waves][ 2x4KB x-stage dbuf | aliased 32x65 f32 scores ].
    // No cross-wave sharing in the K-loop -> NO barriers, counted vmcnt only.
    __shared__ __align__(16) char smem[8 * SLICE];
    __shared__ float hist[NEXP];

    const int tid  = threadIdx.x;
    const int w    = tid >> 6;
    const int lane = tid & 63;
    const int fq   = lane >> 4;   // 0..3
    const int fr   = lane & 15;   // 0..15
    const size_t rowBase = (size_t)blockIdx.x * ROWS;

    if (tid < NEXP) hist[tid] = 0.0f;

    char* myslice = smem + w * SLICE;

    // staging: instr i covers 16B-slots flat = i*64+lane; row=flat>>3 (0..31),
    // phys slot sp=flat&7; source pre-swizzled so LDS holds slot (sp^(row&7)).
    const char* xb = (const char*)(x + (rowBase + (size_t)w * 32) * DIM);
    const char* src[4];
#pragma unroll
    for (int i = 0; i < 4; i++) {
        int flat = i * 64 + lane;
        int row = flat >> 3, sp = flat & 7;
        src[i] = xb + (size_t)row * (DIM * 4) + (sp ^ (row & 7)) * 16;
    }

#define STAGE(BUF, kc)                                                            \
    do {                                                                          \
        _Pragma("unroll")                                                         \
        for (int i_ = 0; i_ < 4; i_++)                                            \
            __builtin_amdgcn_global_load_lds(                                     \
                (const __attribute__((address_space(1))) unsigned int*)(src[i_] + (kc) * 128), \
                (__attribute__((address_space(3))) unsigned int*)(myslice + (BUF) * 4096 + i_ * 1024), \
                16, 0, 0);                                                        \
    } while (0)

    // A-fragment ds_read slot indices (16B units) inside a 4KB buffer
    const int c   = fr & 7;
    const int a00 = fr * 8 + ((fq * 2) ^ c);
    const int a01 = fr * 8 + ((fq * 2 + 1) ^ c);
    const int a10 = (fr + 16) * 8 + ((fq * 2) ^ c);
    const int a11 = (fr + 16) * 8 + ((fq * 2 + 1) ^ c);

    const bf16x8* wfv = (const bf16x8*)wf;

    f32x4 acc[2][4] = {};
    bf16x8 bcur[4];

    // prologue: 8 outstanding vmem (4 bfrag + 4 stage)
#pragma unroll
    for (int nt = 0; nt < 4; nt++) bcur[nt] = wfv[(size_t)nt * 64 + lane];
    STAGE(0, 0);

#define GSTEP(kc, BUF, PREF)                                                      \
    {                                                                             \
        bf16x8 bnext[4];                                                          \
        if (PREF) {                                                               \
            _Pragma("unroll")                                                     \
            for (int nt = 0; nt < 4; nt++)                                        \
                bnext[nt] = wfv[(size_t)(((kc) + 1) * 4 + nt) * 64 + lane];       \
            STAGE((BUF) ^ 1, (kc) + 1);                                           \
            asm volatile("s_waitcnt vmcnt(8)" ::: "memory");                      \
        } else {                                                                  \
            asm volatile("s_waitcnt vmcnt(0)" ::: "memory");                      \
        }                                                                         \
        __builtin_amdgcn_sched_barrier(0);                                        \
        const float4* xt = (const float4*)(myslice + (BUF) * 4096);               \
        bf16x8 af0 = pack_bf16(xt[a00], xt[a01]);                                 \
        bf16x8 af1 = pack_bf16(xt[a10], xt[a11]);                                 \
        _Pragma("unroll")                                                         \
        for (int nt = 0; nt < 4; nt++) {                                          \
            acc[0][nt] = __builtin_amdgcn_mfma_f32_16x16x32_bf16(af0, bcur[nt], acc[0][nt], 0, 0, 0); \
            acc[1][nt] = __builtin_amdgcn_mfma_f32_16x16x32_bf16(af1, bcur[nt], acc[1][nt], 0, 0, 0); \
        }                                                                         \
        if (PREF) {                                                               \
            _Pragma("unroll")                                                     \
            for (int nt = 0; nt < 4; nt++) bcur[nt] = bnext[nt];                  \
        }                                                                         \
    }

    for (int kc = 0; kc < NKC - 2; kc += 2) {
        GSTEP(kc, 0, 1);
        GSTEP(kc + 1, 1, 1);
    }
    GSTEP(NKC - 2, 0, 1);
    GSTEP(NKC - 1, 1, 0);

    // scores (+bias) -> own slice, [32 rows][65] f32 (aliases own stage bufs;
    // all own DMA completed via the final vmcnt(0)).  C/D: col=fr, row=fq*4+r.
    float* sw = (float*)myslice;
    float bv[4];
#pragma unroll
    for (int nt = 0; nt < 4; nt++) bv[nt] = bias[nt * 16 + fr];
#pragma unroll
    for (int mt = 0; mt < 2; mt++) {
        int mbase = mt * 16 + fq * 4;
#pragma unroll
        for (int nt = 0; nt < 4; nt++) {
            int n = nt * 16 + fr;
#pragma unroll
            for (int r = 0; r < 4; r++)
                sw[(mbase + r) * 65 + n] = acc[mt][nt][r] + bv[nt];
        }
    }
    __syncthreads();   // the ONLY block-wide barrier

    // epilogue: one thread per row
    if (tid < ROWS) {
        const float* rp = (const float*)(smem + (tid >> 5) * SLICE) + (tid & 31) * 65;
        float m = rp[0];
#pragma unroll 8
        for (int e = 1; e < NEXP; e++) m = fmaxf(m, rp[e]);

        float tv[8]; int ti[8];
#pragma unroll
        for (int k = 0; k < 8; k++) { tv[k] = -1.0f; ti[k] = 0; }
        float sum = 0.0f;

#pragma unroll 4
        for (int e = 0; e < NEXP; e++) {
            float ev = __expf(rp[e] - m);   // sort by unnormalized e (same order as p)
            sum += ev;
#pragma unroll
            for (int k = 7; k >= 1; k--) {
                bool up   = ev > tv[k - 1];
                bool here = ev > tv[k];
                float nv = up ? tv[k - 1] : (here ? ev : tv[k]);
                int   ni = up ? ti[k - 1] : (here ? e : ti[k]);
                tv[k] = nv; ti[k] = ni;
            }
            bool c0 = ev > tv[0];
            ti[0] = c0 ? e : ti[0];
            tv[0] = c0 ? ev : tv[0];
        }
        float rinv = 1.0f / sum;

        size_t ro = (rowBase + tid) * TOPK;
        *(float4*)(out + ro)     = make_float4(tv[0] * rinv, tv[1] * rinv, tv[2] * rinv, tv[3] * rinv);
        *(float4*)(out + ro + 4) = make_float4(tv[4] * rinv, tv[5] * rinv, tv[6] * rinv, tv[7] * rinv);
        *(float4*)(out + OFF_IDX + ro)     = make_float4((float)ti[0], (float)ti[1], (float)ti[2], (float)ti[3]);
        *(float4*)(out + OFF_IDX + ro + 4) = make_float4((float)ti[4], (float)ti[5], (float)ti[6], (float)ti[7]);
#pragma unroll
        for (int k = 0; k < 8; k++) atomicAdd(&hist[ti[k]], 1.0f);
    }
    __syncthreads();
    if (tid < NEXP) atomicAdd(&out[OFF_USE + tid], hist[tid]);
}

extern "C" void kernel_launch(void* const* d_in, const int* in_sizes, int n_in,
                              void* d_out, int out_size, void* d_ws, size_t ws_size,
                              hipStream_t stream) {
    const float* x    = (const float*)d_in[0];
    const float* W    = (const float*)d_in[1];
    const float* bias = (const float*)d_in[2];
    float* out = (float*)d_out;
    unsigned short* wf = (unsigned short*)d_ws;   // 128 KB fragment-ordered bf16 W

    gate_prep_kernel<<<256, 256, 0, stream>>>(W, wf, out);
    gate_kernel<<<NTOK / ROWS, BLK, 0, stream>>>(x, wf, bias, out);
}